// Round 3
// baseline (36.850 us; speedup 1.0000x reference)
//
#include <hip/hip_runtime.h>
#include <math.h>

// AttentionCropLayer: out[b,c,i,j] = images[b,c,w_off+i,h_off+j] * prof[i]*prof[j]
//   tx = clip(locs[b,0]*224, 44, 180); w_off = floor(tx-44)   (same for h via locs[b,1])
//   prof[r] = sigmoid(10*r) - sigmoid(10*(r-88))
// Shapes: images [128,16,224,224] f32, locs [128,2] f32, out [128,16,88,88] f32.
// Memory-bound: ~63 MB useful read (+~25% unaligned-line overfetch) + 63 MB write.
// R1: 27.45 us (~5.2 TB/s physical). R2: nontemporal + 32B/thread-iter
// (compile fix: clang ext_vector float4, HIP_vector_type rejected by builtin).

#define TLn   44
#define CROP  88
#define INSZ  224
#define NCH   16
#define PLANE (CROP * CROP)       // 7744
#define OCT   (PLANE / 8)         // 968 8-float chunks per plane (88 % 8 == 0)

typedef float f32x4 __attribute__((ext_vector_type(4)));

__global__ __launch_bounds__(256)
void attention_crop_kernel(const float* __restrict__ images,
                           const float* __restrict__ locs,
                           float* __restrict__ out)
{
    __shared__ float prof[CROP];

    const int bc = blockIdx.x;        // b * NCH + c
    const int b  = bc >> 4;
    const int t  = threadIdx.x;

    // Mask profile (identical for all blocks; 88 expf's per block is negligible).
    if (t < CROP) {
        float r  = (float)t;
        float s1 = 1.0f / (1.0f + expf(-10.0f * r));
        float s2 = 1.0f / (1.0f + expf(-10.0f * (r - (float)CROP)));
        prof[t] = s1 - s2;
    }

    // Per-batch crop offsets — every lane computes them (locs is tiny, L2-hot).
    const float tx = fminf(fmaxf(locs[2 * b]     * 224.0f, (float)TLn), (float)(INSZ - TLn));
    const float ty = fminf(fmaxf(locs[2 * b + 1] * 224.0f, (float)TLn), (float)(INSZ - TLn));
    const int w_off = (int)floorf(tx - (float)TLn);   // value in [0,136], trunc == floor
    const int h_off = (int)floorf(ty - (float)TLn);

    __syncthreads();

    const float* __restrict__ src =
        images + ((size_t)bc * INSZ + (size_t)w_off) * INSZ + h_off;
    float* __restrict__ dst = out + (size_t)bc * PLANE;

    // Each thread: 8 consecutive output floats per iteration (never crosses a
    // crop row since 88 % 8 == 0). Input is only 4B-aligned (h_off arbitrary)
    // -> scalar nontemporal loads; output chunk is 32B-aligned -> two 16B
    // nontemporal stores. Everything is single-use streaming: nt frees L2.
    for (int q = t; q < OCT; q += 256) {
        const int e = q * 8;
        const int i = e / CROP;
        const int j = e - i * CROP;

        const float* __restrict__ s = src + (size_t)i * INSZ + j;
        float v[8];
        #pragma unroll
        for (int k = 0; k < 8; ++k)
            v[k] = __builtin_nontemporal_load(s + k);

        const float pi = prof[i];
        f32x4 a, c;
        a.x = v[0] * (pi * prof[j]);
        a.y = v[1] * (pi * prof[j + 1]);
        a.z = v[2] * (pi * prof[j + 2]);
        a.w = v[3] * (pi * prof[j + 3]);
        c.x = v[4] * (pi * prof[j + 4]);
        c.y = v[5] * (pi * prof[j + 5]);
        c.z = v[6] * (pi * prof[j + 6]);
        c.w = v[7] * (pi * prof[j + 7]);

        __builtin_nontemporal_store(a, reinterpret_cast<f32x4*>(dst + e));
        __builtin_nontemporal_store(c, reinterpret_cast<f32x4*>(dst + e + 4));
    }
}

extern "C" void kernel_launch(void* const* d_in, const int* in_sizes, int n_in,
                              void* d_out, int out_size, void* d_ws, size_t ws_size,
                              hipStream_t stream)
{
    const float* images = (const float*)d_in[0];
    const float* locs   = (const float*)d_in[1];
    float*       out    = (float*)d_out;

    const int B = in_sizes[1] / 2;     // 128
    dim3 grid(B * NCH);                // 2048 blocks, one per (b, c) plane
    attention_crop_kernel<<<grid, 256, 0, stream>>>(images, locs, out);
}

// Round 4
// 27.583 us; speedup vs baseline: 1.3360x; 1.3360x over previous
//
#include <hip/hip_runtime.h>
#include <math.h>

// AttentionCropLayer: out[b,c,i,j] = images[b,c,w_off+i,h_off+j] * prof[i]*prof[j]
//   tx = clip(locs[b,0]*224, 44, 180); w_off = floor(tx-44)   (same for h via locs[b,1])
//   prof[r] = sigmoid(10*r) - sigmoid(10*(r-88))
// In f32, prof[r] == 1.0f exactly for r not in {0,1,87} (r=86 rounds to 1.0f):
//   prof[0]=0.5, prof[1]=prof[87]=1/(1+e^-10)=0.9999546f. So mask = predicated
//   edge multiplies; no LDS, no expf per element.
// Misalignment phase s = h_off & 3 is uniform per block (all other index terms
// are multiples of 4) -> aligned float4 loads at (src - s) + compile-time
// funnel shift, via 4 template instantiations.
// R1: 27.45us (scalar cached loads). R2/3: nt hints -36% (L1 bypass on strided
// scalar loads -> 8x L2 re-fetch). R4: aligned-vec loads + maskless edges.

#define TLn    44
#define CROP   88
#define INSZ   224
#define NCH    16
#define IPLANE (INSZ * INSZ)      // 50176
#define PLANE  (CROP * CROP)      // 7744
#define OCT    (PLANE / 8)        // 968 8-float chunks (88 % 8 == 0)

#define PEDGE 0.9999546021312976f // 1/(1+exp(-10)) in f32

typedef float f32x4 __attribute__((ext_vector_type(4)));

template<int S>
__device__ __forceinline__ void crop_plane(const float* __restrict__ srcA,
                                           float* __restrict__ dst, int t)
{
    // srcA = plane src shifted down by S elements -> 16B-aligned rows.
    int e = t * 8;            // output element index
    int i = e / CROP;         // one magic-mul at entry; incremental after
    int j = e - i * CROP;

    for (int q = t; q < OCT; q += 256) {
        const float* __restrict__ s4 = srcA + i * INSZ + j;   // 16B aligned

        f32x4 v0 = *reinterpret_cast<const f32x4*>(s4);
        f32x4 v1 = *reinterpret_cast<const f32x4*>(s4 + 4);
        float ex[3];
        #pragma unroll
        for (int k = 0; k < S; ++k) ex[k] = s4[8 + k];        // only used tail

        // w[k] = source element (j+k) of the crop row; all indices fold.
        float w[8];
        #pragma unroll
        for (int k = 0; k < 8; ++k) {
            const int p = k + S;
            w[k] = (p < 4) ? v0[p] : (p < 8) ? v1[p - 4] : ex[p - 8];
        }

        // Row factor: 0.5 (i==0), PEDGE (i==1 or 87), else 1.0.
        const float fi = (i == 0) ? 0.5f
                       : ((i == 1) | (i == 87)) ? PEDGE : 1.0f;
        #pragma unroll
        for (int k = 0; k < 8; ++k) w[k] *= fi;

        // Column factor: only chunks j==0 (cols 0,1) and j==80 (col 87).
        if (j == 0)  { w[0] *= 0.5f; w[1] *= PEDGE; }
        if (j == 80) { w[7] *= PEDGE; }

        f32x4 a = { w[0], w[1], w[2], w[3] };
        f32x4 c = { w[4], w[5], w[6], w[7] };
        *reinterpret_cast<f32x4*>(dst + e)     = a;
        *reinterpret_cast<f32x4*>(dst + e + 4) = c;

        // advance by 256 chunks = 2048 elements = 23 rows + 24 cols
        e += 2048;
        i += 23; j += 24;
        if (j >= CROP) { j -= CROP; ++i; }
    }
}

__global__ __launch_bounds__(256)
void attention_crop_kernel(const float* __restrict__ images,
                           const float* __restrict__ locs,
                           float* __restrict__ out)
{
    const int bc = blockIdx.x;        // b * NCH + c
    const int b  = bc >> 4;
    const int t  = threadIdx.x;

    // Same float32 arithmetic as the reference (values >= 0, trunc == floor).
    const float tx = fminf(fmaxf(locs[2 * b]     * 224.0f, (float)TLn), (float)(INSZ - TLn));
    const float ty = fminf(fmaxf(locs[2 * b + 1] * 224.0f, (float)TLn), (float)(INSZ - TLn));
    const int w_off = (int)floorf(tx - (float)TLn);
    const int h_off = (int)floorf(ty - (float)TLn);

    const int s = h_off & 3;          // uniform per block; s <= h_off (no underflow)
    const float* srcA = images + (size_t)bc * IPLANE + (size_t)w_off * INSZ + (h_off - s);
    float* dst = out + (size_t)bc * PLANE;

    switch (s) {
        case 0: crop_plane<0>(srcA, dst, t); break;
        case 1: crop_plane<1>(srcA, dst, t); break;
        case 2: crop_plane<2>(srcA, dst, t); break;
        default: crop_plane<3>(srcA, dst, t); break;
    }
}

extern "C" void kernel_launch(void* const* d_in, const int* in_sizes, int n_in,
                              void* d_out, int out_size, void* d_ws, size_t ws_size,
                              hipStream_t stream)
{
    const float* images = (const float*)d_in[0];
    const float* locs   = (const float*)d_in[1];
    float*       out    = (float*)d_out;

    const int B = in_sizes[1] / 2;     // 128
    dim3 grid(B * NCH);                // 2048 blocks, one per (b, c) plane
    attention_crop_kernel<<<grid, 256, 0, stream>>>(images, locs, out);
}